// Round 7
// baseline (214.350 us; speedup 1.0000x reference)
//
#include <hip/hip_runtime.h>

typedef unsigned short u16;
typedef unsigned int   u32;
typedef unsigned long long u64;
typedef __bf16 bf16x8 __attribute__((ext_vector_type(8)));
typedef float  f32x4  __attribute__((ext_vector_type(4)));
typedef u32    u32x4  __attribute__((ext_vector_type(4)));
typedef u16    u16x4  __attribute__((ext_vector_type(4)));
typedef u16    u16x8v __attribute__((ext_vector_type(8)));

#define R_DIM 400
#define F_DIM 256
#define M_TOT 51200

__device__ __forceinline__ u16 f2bf(float f) {
    union { float f; u32 i; } x; x.f = f;
    u32 r = x.i + 0x7FFFu + ((x.i >> 16) & 1u);   // RNE
    return (u16)(r >> 16);
}

// ---------------------------------------------------------------------------
// Kernel 1: convert fp32 W -> bf16 B-fragments (unchanged, verified).
// ---------------------------------------------------------------------------
__global__ __launch_bounds__(256) void wprep_f32(const float* __restrict__ W,
                                                 u16* __restrict__ Wf) {
    int g  = blockIdx.x * 256 + threadIdx.x;   // 0..8191
    int ks = g >> 10;
    int T  = (g >> 6) & 15;
    int L  = g & 63;
    int n  = T * 16 + (L & 15);
    int k  = ks * 32 + (L >> 4) * 8;
    const float* wp = W + (size_t)n * F_DIM + k;
    float4 lo = *(const float4*)wp;
    float4 hi = *(const float4*)(wp + 4);
    u16x8v t;
    t[0] = f2bf(lo.x); t[1] = f2bf(lo.y); t[2] = f2bf(lo.z); t[3] = f2bf(lo.w);
    t[4] = f2bf(hi.x); t[5] = f2bf(hi.y); t[6] = f2bf(hi.z); t[7] = f2bf(hi.w);
    *(u16x8v*)(Wf + (size_t)g * 8) = t;
}

// ---------------------------------------------------------------------------
// Ballot-based ranks (verified): rank(c) = #{j: A[j]>A[c]} + #{j<c: A[j]==A[c]}.
// ---------------------------------------------------------------------------
__device__ __forceinline__ void compute_slots(float4 v0, float4 v1r, int lane,
                                              int diag, u32 es[7], u32* dup_out) {
    float4 v1 = v1r;
    if (lane >= 36) { v1.x = -1.f; v1.y = -1.f; v1.z = -1.f; v1.w = -1.f; } // A in [0,1)
    float refs[6];
    refs[0] = __shfl(v0.x, 0);   // col 0
    refs[1] = __shfl(v0.x, 2);   // col 8
    refs[2] = __shfl(v0.y, 2);   // col 9
    refs[3] = __shfl(v0.z, 2);   // col 10
    refs[4] = __shfl(v0.w, 2);   // col 11
    refs[5] = __shfl(v0.x, 3);   // col 12
    const int cols[6] = {0, 8, 9, 10, 11, 12};
    float e0[4] = {v0.x, v0.y, v0.z, v0.w};
    float e1[4] = {v1.x, v1.y, v1.z, v1.w};
    u32 cnt[6];
#pragma unroll
    for (int k = 0; k < 6; k++) {
        int c = 0;
#pragma unroll
        for (int jj = 0; jj < 4; jj++) {
            int j = (lane << 2) + jj;
            c += __popcll(__ballot(e0[jj] > refs[k] ||
                                   (e0[jj] == refs[k] && j < cols[k])));
            c += __popcll(__ballot(e1[jj] > refs[k]));   // j>=256 > cols[k] always
        }
        cnt[k] = (u32)c;
    }
    bool dup = (diag == (int)cnt[0]) | (diag == (int)cnt[1]) | (diag == (int)cnt[2]) |
               (diag == (int)cnt[3]) | (diag == (int)cnt[4]) | (diag == (int)cnt[5]);
#pragma unroll
    for (int s = 0; s < 6; s++) es[s] = cnt[s];
    es[6] = (u32)diag;
    *dup_out = dup ? 1u : 0u;
}

// Element e of the row held wave-wide in (v0, v1): uniform-index extract.
// e uniform (SGPR) -> cndmask selects + one readlane/shfl; bit-exact vs memory.
// v1 garbage lanes (>=36) are never sources: e in [256,400) -> src lane <= 35.
__device__ __forceinline__ float row_elem(float4 v0, float4 v1, u32 e) {
    const bool hi  = e >= 256;
    const int comp = (int)(e & 3);
    const int src  = (int)((hi ? e - 256 : e) >> 2);
    float c0 = hi ? v1.x : v0.x;
    float c1 = hi ? v1.y : v0.y;
    float c2 = hi ? v1.z : v0.z;
    float c3 = hi ? v1.w : v0.w;
    float val = (comp == 0) ? c0 : (comp == 1) ? c1 : (comp == 2) ? c2 : c3;
    return __shfl(val, src);
}

// ---------------------------------------------------------------------------
// Kernel 2: GATHER v2 — 2 rows per wave, batched phases, zero memory w-loads.
// 6400 blocks x 256 threads (4 waves, each an independent row-pair).
// Pair p -> rows 2p, 2p+1 (always same bh: 2p+1 odd, bh bounds are mult. of 400).
// XCD swizzle: XCD x owns pairs [x*3200,(x+1)*3200) == rows [x*6400,(x+1)*6400).
// Phases: {4 A-loads} wait {slots x2 (ballots)} {14 feats loads + 14 reg-w} wait
// {consume x2}. w[s] extracted from the in-register row (v_readlane) — the
// uniform-address scalar-load serialization of R6 is eliminated.
// Bit-identical agg: same ballot formula, summation order, f2bf.
// ---------------------------------------------------------------------------
__global__ __launch_bounds__(256) void gcn_gather(const float* __restrict__ A,
                                                  const float* __restrict__ feats,
                                                  u16* __restrict__ agg) {
    const int tid = threadIdx.x, wid = tid >> 6, lane = tid & 63;
    const int bid = (int)blockIdx.x;
    const int p    = ((bid & 7) * 800 + (bid >> 3)) * 4 + wid;  // pair id, 25600 total
    const int row0 = p * 2;
    const int bh   = row0 / R_DIM;
    const int dia0 = row0 - bh * R_DIM;

    // ---- phase 1: all 4 A-row loads up front ----
    const float* Ar0 = A + (size_t)row0 * R_DIM;
    const float* Ar1 = Ar0 + R_DIM;
    float4 u0 = *(const float4*)(Ar0 + lane * 4);
    float4 u1 = *(const float4*)(Ar0 + (lane < 36 ? 256 + lane * 4 : 0));
    float4 t0 = *(const float4*)(Ar1 + lane * 4);
    float4 t1 = *(const float4*)(Ar1 + (lane < 36 ? 256 + lane * 4 : 0));

    // ---- phase 2: two independent slot computations (interleavable) ----
    u32 esA[7], esB[7], dupA, dupB;
    compute_slots(u0, u1, lane, dia0,     esA, &dupA);
    compute_slots(t0, t1, lane, dia0 + 1, esB, &dupB);

    // ---- phase 3: issue all 14 feats loads; extract all 14 w from registers ----
    const float* fb = feats + (size_t)bh * R_DIM * F_DIM + lane * 4;
    float4 fA[7], fB[7];
#pragma unroll
    for (int s = 0; s < 7; s++) fA[s] = *(const float4*)(fb + (size_t)esA[s] * F_DIM);
#pragma unroll
    for (int s = 0; s < 7; s++) fB[s] = *(const float4*)(fb + (size_t)esB[s] * F_DIM);

    float wA[7], wB[7];
#pragma unroll
    for (int s = 0; s < 7; s++) wA[s] = row_elem(u0, u1, esA[s]);
#pragma unroll
    for (int s = 0; s < 7; s++) wB[s] = row_elem(t0, t1, esB[s]);

    // ---- phase 4: consume both rows (same summation order as verified) ----
    {
        float a0 = 0.f, a1 = 0.f, a2 = 0.f, a3 = 0.f;
#pragma unroll
        for (int s = 0; s < 7; s++) {
            float ws = (s == 6 && dupA) ? 0.f : wA[s];
            a0 += ws * fA[s].x; a1 += ws * fA[s].y; a2 += ws * fA[s].z; a3 += ws * fA[s].w;
        }
        u16x4 st = { f2bf(a0), f2bf(a1), f2bf(a2), f2bf(a3) };
        *(u16x4*)(agg + (size_t)row0 * F_DIM + lane * 4) = st;
    }
    {
        float a0 = 0.f, a1 = 0.f, a2 = 0.f, a3 = 0.f;
#pragma unroll
        for (int s = 0; s < 7; s++) {
            float ws = (s == 6 && dupB) ? 0.f : wB[s];
            a0 += ws * fB[s].x; a1 += ws * fB[s].y; a2 += ws * fB[s].z; a3 += ws * fB[s].w;
        }
        u16x4 st = { f2bf(a0), f2bf(a1), f2bf(a2), f2bf(a3) };
        *(u16x4*)(agg + (size_t)(row0 + 1) * F_DIM + lane * 4) = st;
    }
}

// ---------------------------------------------------------------------------
// Kernel 3: GEMM — unchanged from R6 (verified; ~30-35us, near traffic floor).
// ---------------------------------------------------------------------------
__global__ __launch_bounds__(256, 4) void gcn_gemm(const u16*  __restrict__ agg,
                                                   const u16*  __restrict__ Wf,
                                                   const float* __restrict__ bias,
                                                   const float* __restrict__ feats,
                                                   float* __restrict__ out) {
    __shared__ __align__(16) u16 probeA[16][32];
    __shared__ __align__(16) u16 probeB[16][32];

    const int tid = threadIdx.x, wid = tid >> 6, lane = tid & 63;
    const int bid = (int)blockIdx.x;
    const int m0  = ((bid & 7) * 200 + (bid >> 3)) * 32;
    const int kg  = (lane >> 4) << 3;
    const int mt  = wid & 1;         // m-tile within block
    const int nh  = wid >> 1;        // n-half: n-tiles nh*8 .. nh*8+7

    // probe tiles: A[m][0]=m, A[m][1]=1; B[n][0]=16, B[n][1]=n  -> D=16m+n
    for (int e = tid; e < 512; e += 256) {
        int r = e >> 5, k = e & 31;
        probeA[r][k] = (k == 0) ? f2bf((float)r) : ((k == 1) ? f2bf(1.0f) : (u16)0);
        probeB[r][k] = (k == 0) ? f2bf(16.0f)    : ((k == 1) ? f2bf((float)r) : (u16)0);
    }
    __syncthreads();

    // ---- probe MFMA: decode true per-register (row,col) ----
    int rowi[4], coli[4];
    {
        bf16x8 pa = *(const bf16x8*)&probeA[lane & 15][kg];
        bf16x8 pb = *(const bf16x8*)&probeB[lane & 15][kg];
        f32x4 pd = {0.f, 0.f, 0.f, 0.f};
        pd = __builtin_amdgcn_mfma_f32_16x16x32_bf16(pa, pb, pd, 0, 0, 0);
#pragma unroll
        for (int reg = 0; reg < 4; reg++) {
            int v = (int)(pd[reg] + 0.5f);
            rowi[reg] = v >> 4;
            coli[reg] = v & 15;
        }
    }

    // ---- MFMA K-loop: af per-lane direct from global agg ----
    f32x4 acc[8];
#pragma unroll
    for (int nt = 0; nt < 8; nt++) acc[nt] = (f32x4){0.f, 0.f, 0.f, 0.f};

    const u16* ab = agg + (size_t)(m0 + mt * 16 + (lane & 15)) * F_DIM + kg;
#pragma unroll
    for (int ks = 0; ks < 8; ks++) {
        bf16x8 af = *(const bf16x8*)(ab + ks * 32);
#pragma unroll
        for (int nt = 0; nt < 8; nt++) {
            int T = nh * 8 + nt;
            u32x4 v = *(const u32x4*)(Wf + ((size_t)(ks * 16 + T) * 64 + lane) * 8);
            bf16x8 b = __builtin_bit_cast(bf16x8, v);
            acc[nt] = __builtin_amdgcn_mfma_f32_16x16x32_bf16(af, b, acc[nt], 0, 0, 0);
        }
    }

    // ---- epilogue: relu(acc + b) + feats -> out (fp32) ----
#pragma unroll
    for (int nt = 0; nt < 8; nt++) {
        int nb = (nh * 8 + nt) * 16;
#pragma unroll
        for (int reg = 0; reg < 4; reg++) {
            int gn = nb + coli[reg];
            float bn = bias[gn];
            int gm = m0 + mt * 16 + rowi[reg];
            size_t off = (size_t)gm * F_DIM + gn;
            out[off] = fmaxf(acc[nt][reg] + bn, 0.f) + feats[off];
        }
    }
}

extern "C" void kernel_launch(void* const* d_in, const int* in_sizes, int n_in,
                              void* d_out, int out_size, void* d_ws, size_t ws_size,
                              hipStream_t stream) {
    const float* A     = (const float*)d_in[0];   // [16,8,400,400] fp32
    const float* feats = (const float*)d_in[1];   // [16,8,400,256] fp32
    const float* W     = (const float*)d_in[2];   // [256,256] fp32
    const float* bias  = (const float*)d_in[3];   // [256] fp32
    float* out = (float*)d_out;                   // [16,8,400,256] fp32

    u16* Wf  = (u16*)d_ws;                                  // 128 KB
    u16* agg = (u16*)((char*)d_ws + (size_t)128 * 1024);    // 26.2 MB bf16 agg

    wprep_f32 <<<32,   256, 0, stream>>>(W, Wf);
    gcn_gather<<<6400, 256, 0, stream>>>(A, feats, agg);
    gcn_gemm  <<<1600, 256, 0, stream>>>(agg, Wf, bias, feats, out);
}